// Round 14
// baseline (154.326 us; speedup 1.0000x reference)
//
#include <hip/hip_runtime.h>

#define E  1024
#define H  64
#define BB 8
#define TT 2048

typedef __attribute__((ext_vector_type(8)))  short bf16x8;
typedef __attribute__((ext_vector_type(4)))  float f32x4;
typedef __attribute__((ext_vector_type(16))) float f32x16;
typedef __attribute__((ext_vector_type(8)))  short short8;
typedef __attribute__((ext_vector_type(4)))  short short4v;
typedef __attribute__((ext_vector_type(4)))  unsigned u32x4;

__device__ __forceinline__ short f2bf(float f) {
    union { float f; unsigned u; } v; v.f = f;
    unsigned r = v.u + 0x7FFFu + ((v.u >> 16) & 1u);   // RNE
    return (short)(r >> 16);
}

// fast 2^x via the HW transcendental (no HIP __exp2f intrinsic exists)
__device__ __forceinline__ float fexp2(float x) {
    float r;
    asm("v_exp_f32 %0, %1" : "=v"(r) : "v"(x));
    return r;
}

// 8 fp32 -> bf16x8 via 4x v_cvt_pk_bf16_f32
__device__ __forceinline__ bf16x8 cvt8(float4 a0, float4 a1) {
    unsigned w0, w1, w2, w3;
    asm("v_cvt_pk_bf16_f32 %0, %1, %2" : "=v"(w0) : "v"(a0.x), "v"(a0.y));
    asm("v_cvt_pk_bf16_f32 %0, %1, %2" : "=v"(w1) : "v"(a0.z), "v"(a0.w));
    asm("v_cvt_pk_bf16_f32 %0, %1, %2" : "=v"(w2) : "v"(a1.x), "v"(a1.y));
    asm("v_cvt_pk_bf16_f32 %0, %1, %2" : "=v"(w3) : "v"(a1.z), "v"(a1.w));
    u32x4 u = {w0, w1, w2, w3};
    bf16x8 r;
    __builtin_memcpy(&r, &u, 16);
    return r;
}

// ---- pack W into B-fragment layout for mfma_f32_16x16x32_bf16 ----
__global__ __launch_bounds__(256)
void pack_w(const float* __restrict__ Wq, const float* __restrict__ Wk,
            const float* __restrict__ Wv, short* __restrict__ Wb)
{
    const int t  = blockIdx.x * 256 + threadIdx.x;   // 24576 total
    const int l  = t & 63;
    const int f  = (t >> 6) % 12;
    const int kc = t / 768;                          // kchunk 0..31
    const float* W = (f < 4) ? Wq : ((f < 8) ? Wk : Wv);
    const int e0 = kc * 32 + ((l >> 4) << 3);
    const int n  = ((f & 3) << 4) + (l & 15);
    short8 o;
    #pragma unroll
    for (int j = 0; j < 8; ++j) o[j] = f2bf(W[(e0 + j) * 64 + n]);
    *(short8*)&Wb[(size_t)t * 8] = o;
}

// ---- proj v5 (unchanged): 64 rows/block, B amortized over 4 row-tiles ----
__global__ __launch_bounds__(256)
void proj_v5(const float* __restrict__ x, const short* __restrict__ Wb,
             short* __restrict__ q, short* __restrict__ k, short* __restrict__ vt)
{
    __shared__ short xs[64 * 1024];      // 128 KB bf16
    const int t = threadIdx.x;
    const long row0 = (long)blockIdx.x * 64;

    #pragma unroll
    for (int b8 = 0; b8 < 4; ++b8) {
        float4 va[16];
        #pragma unroll
        for (int j = 0; j < 8; ++j) {
            const int u = (b8 * 8 + j) * 256 + t;
            const int r = u >> 7, c = u & 127;
            const float* p = x + (row0 + r) * E + c * 8;
            va[j * 2]     = *(const float4*)(p);
            va[j * 2 + 1] = *(const float4*)(p + 4);
        }
        #pragma unroll
        for (int j = 0; j < 8; ++j) {
            const int u = (b8 * 8 + j) * 256 + t;
            const int r = u >> 7, c = u & 127;
            *(bf16x8*)&xs[(r * 128 + (c ^ (r & 7))) * 8] = cvt8(va[j * 2], va[j * 2 + 1]);
        }
    }
    __syncthreads();

    const int l   = t & 63;
    const int fg  = t >> 6;
    const int l15 = l & 15, g = l >> 4;
    const int swz = l15 & 7;

    f32x4 acc[4][3] = {};
    const short* wb = Wb + ((size_t)(fg * 3) * 64 + l) * 8;

    #pragma unroll 4
    for (int kc = 0; kc < 32; ++kc) {
        const short* wp = wb + (size_t)kc * 12 * 512;
        bf16x8 b0 = *(const bf16x8*)(wp);
        bf16x8 b1 = *(const bf16x8*)(wp + 512);
        bf16x8 b2 = *(const bf16x8*)(wp + 1024);
        const int cu = (kc * 4 + g) ^ swz;
        #pragma unroll
        for (int rt = 0; rt < 4; ++rt) {
            bf16x8 af = *(const bf16x8*)&xs[((rt * 16 + l15) * 128 + cu) * 8];
            acc[rt][0] = __builtin_amdgcn_mfma_f32_16x16x32_bf16(af, b0, acc[rt][0], 0, 0, 0);
            acc[rt][1] = __builtin_amdgcn_mfma_f32_16x16x32_bf16(af, b1, acc[rt][1], 0, 0, 0);
            acc[rt][2] = __builtin_amdgcn_mfma_f32_16x16x32_bf16(af, b2, acc[rt][2], 0, 0, 0);
        }
    }

    #pragma unroll
    for (int rt = 0; rt < 4; ++rt) {
        const long rowb = row0 + rt * 16;
        #pragma unroll
        for (int fi = 0; fi < 3; ++fi) {
            const int f = fg * 3 + fi;
            const int m = f >> 2;
            const int h = ((f & 3) << 4) + l15;
            if (m == 2) {
                const long row = rowb + g * 4;
                const long bb = row >> 11;
                const int  t0 = (int)(row & 2047);
                short4v pkt;
                #pragma unroll
                for (int r = 0; r < 4; ++r) pkt[r] = f2bf(acc[rt][fi][r]);
                *(short4v*)&vt[(bb * 64 + h) * TT + t0] = pkt;
            } else {
                short* base = (m == 0) ? q : k;
                const float sc = (m == 0) ? (0.125f * 1.44269504f) : 1.0f;
                #pragma unroll
                for (int r = 0; r < 4; ++r)
                    base[(rowb + g * 4 + r) * 64 + h] = f2bf(acc[rt][fi][r] * sc);
            }
        }
    }
}

// ---- ABLATION 1: pure x ingest (grid-stride streaming cvt copy), 6 reps ----
__global__ __launch_bounds__(256)
void abl_copy(const float* __restrict__ x, short* __restrict__ dummy)
{
    const long nvec = (long)BB * TT * E / 8;          // 2,097,152 units of 8
    const long stride = (long)gridDim.x * 256;
    for (int rep = 0; rep < 6; ++rep) {
        for (long i = (long)blockIdx.x * 256 + threadIdx.x; i < nvec; i += stride) {
            const float* p = x + i * 8;
            float4 a0 = *(const float4*)(p);
            float4 a1 = *(const float4*)(p + 4);
            *(bf16x8*)&dummy[i * 8] = cvt8(a0, a1);
        }
        asm volatile("" ::: "memory");   // block LICM/dead-store elim across reps
    }
}

// ---- ABLATION 2: proj_v5 compute+store phase only (no staging; dummy out) --
__global__ __launch_bounds__(256)
void abl_comp(const short* __restrict__ Wb,
              short* __restrict__ q, short* __restrict__ k, short* __restrict__ vt)
{
    __shared__ short xs[64 * 1024];      // uninitialized: values irrelevant
    const int t = threadIdx.x;
    const long row0 = (long)blockIdx.x * 64;
    __syncthreads();

    const int l   = t & 63;
    const int fg  = t >> 6;
    const int l15 = l & 15, g = l >> 4;
    const int swz = l15 & 7;

    f32x4 acc[4][3] = {};
    const short* wb = Wb + ((size_t)(fg * 3) * 64 + l) * 8;

    #pragma unroll 4
    for (int kc = 0; kc < 32; ++kc) {
        const short* wp = wb + (size_t)kc * 12 * 512;
        bf16x8 b0 = *(const bf16x8*)(wp);
        bf16x8 b1 = *(const bf16x8*)(wp + 512);
        bf16x8 b2 = *(const bf16x8*)(wp + 1024);
        const int cu = (kc * 4 + g) ^ swz;
        #pragma unroll
        for (int rt = 0; rt < 4; ++rt) {
            bf16x8 af = *(const bf16x8*)&xs[((rt * 16 + l15) * 128 + cu) * 8];
            acc[rt][0] = __builtin_amdgcn_mfma_f32_16x16x32_bf16(af, b0, acc[rt][0], 0, 0, 0);
            acc[rt][1] = __builtin_amdgcn_mfma_f32_16x16x32_bf16(af, b1, acc[rt][1], 0, 0, 0);
            acc[rt][2] = __builtin_amdgcn_mfma_f32_16x16x32_bf16(af, b2, acc[rt][2], 0, 0, 0);
        }
    }

    #pragma unroll
    for (int rt = 0; rt < 4; ++rt) {
        const long rowb = row0 + rt * 16;
        #pragma unroll
        for (int fi = 0; fi < 3; ++fi) {
            const int f = fg * 3 + fi;
            const int m = f >> 2;
            const int h = ((f & 3) << 4) + l15;
            if (m == 2) {
                const long row = rowb + g * 4;
                const long bb = row >> 11;
                const int  t0 = (int)(row & 2047);
                short4v pkt;
                #pragma unroll
                for (int r = 0; r < 4; ++r) pkt[r] = f2bf(acc[rt][fi][r]);
                *(short4v*)&vt[(bb * 64 + h) * TT + t0] = pkt;
            } else {
                short* base = (m == 0) ? q : k;
                const float sc = (m == 0) ? (0.125f * 1.44269504f) : 1.0f;
                #pragma unroll
                for (int r = 0; r < 4; ++r)
                    base[(rowb + g * 4 + r) * 64 + h] = f2bf(acc[rt][fi][r] * sc);
            }
        }
    }
}

// ---- 32x32 swapped-QK^T flash attention (unchanged) ----
__global__ __launch_bounds__(512)
void attn_v8(const short* __restrict__ qg,
             const short* __restrict__ kg,
             const short* __restrict__ vtg,
             float* __restrict__ out)
{
    __shared__ float Op[8][32][66];
    __shared__ float Ml[8][32][2];

    const int t   = threadIdx.x;
    const int L   = t & 63;
    const int w   = t >> 6;
    const int bid = blockIdx.x;
    const int b   = bid & 7;
    const int pr  = bid >> 3;
    const int l31 = L & 31, hi = L >> 5;

    const int stA = pr, stB = 63 - pr;
    const int nA = stA + 1;
    int WA = (8 * nA + 32) / 65;
    WA = WA < 1 ? 1 : (WA > 7 ? 7 : WA);
    const int WB = 8 - WA;

    const bool isB  = (w >= WA);
    const int  st   = isB ? stB : stA;
    const int  q0   = st * 32;
    const int  strd = isB ? WB : WA;
    const int  c0   = isB ? (w - WA) : w;

    bf16x8 qf[4];
    {
        const short* qp = qg + ((long)b * TT + q0 + l31) * 64 + hi * 8;
        qf[0] = *(const bf16x8*)(qp);
        qf[1] = *(const bf16x8*)(qp + 16);
        qf[2] = *(const bf16x8*)(qp + 32);
        qf[3] = *(const bf16x8*)(qp + 48);
    }

    f32x16 o0 = {}, o1 = {};
    float mrun = -1e30f, lrun = 0.f;

    const short* kbase = kg  + ((long)b * TT + l31) * 64 + hi * 8;
    const short* vbase = vtg + ((long)b * 64 + l31) * TT + hi * 8;

    for (int ci = c0; ci <= st; ci += strd) {
        const int kvs = ci * 32;
        const short* kp = kbase + (long)kvs * 64;
        bf16x8 kf0 = *(const bf16x8*)(kp);
        bf16x8 kf1 = *(const bf16x8*)(kp + 16);
        bf16x8 kf2 = *(const bf16x8*)(kp + 32);
        bf16x8 kf3 = *(const bf16x8*)(kp + 48);
        const short* vp = vbase + kvs;
        bf16x8 vf00 = *(const bf16x8*)(vp);
        bf16x8 vf01 = *(const bf16x8*)(vp + 16);
        bf16x8 vf10 = *(const bf16x8*)(vp + 32 * TT);
        bf16x8 vf11 = *(const bf16x8*)(vp + 32 * TT + 16);

        f32x16 s = {};
        __builtin_amdgcn_s_setprio(1);
        s = __builtin_amdgcn_mfma_f32_32x32x16_bf16(kf0, qf[0], s, 0, 0, 0);
        s = __builtin_amdgcn_mfma_f32_32x32x16_bf16(kf1, qf[1], s, 0, 0, 0);
        s = __builtin_amdgcn_mfma_f32_32x32x16_bf16(kf2, qf[2], s, 0, 0, 0);
        s = __builtin_amdgcn_mfma_f32_32x32x16_bf16(kf3, qf[3], s, 0, 0, 0);
        __builtin_amdgcn_s_setprio(0);

        if (kvs == q0) {
            #pragma unroll
            for (int r = 0; r < 16; ++r) {
                const int crow = (r & 3) + 8 * (r >> 2) + 4 * hi;
                if (crow > l31) s[r] = -1e30f;
            }
        }
        float m01 = fmaxf(s[0], s[1]),   m23 = fmaxf(s[2], s[3]);
        float m45 = fmaxf(s[4], s[5]),   m67 = fmaxf(s[6], s[7]);
        float m89 = fmaxf(s[8], s[9]),   mab = fmaxf(s[10], s[11]);
        float mcd = fmaxf(s[12], s[13]), mef = fmaxf(s[14], s[15]);
        float mloc = fmaxf(fmaxf(fmaxf(m01, m23), fmaxf(m45, m67)),
                           fmaxf(fmaxf(m89, mab), fmaxf(mcd, mef)));
        mloc = fmaxf(mloc, __shfl_xor(mloc, 32));
        if (__any(mloc > mrun + 8.f)) {
            const float mnew = fmaxf(mrun, mloc);
            const float a = fexp2(mrun - mnew);
            mrun = mnew;
            lrun *= a;
            #pragma unroll
            for (int r = 0; r < 16; ++r) { o0[r] *= a; o1[r] *= a; }
        }
        #pragma unroll
        for (int r = 0; r < 16; ++r) s[r] = fexp2(s[r] - mrun);
        {
            float s01 = (s[0] + s[1]) + (s[2] + s[3]);
            float s23 = (s[4] + s[5]) + (s[6] + s[7]);
            float s45 = (s[8] + s[9]) + (s[10] + s[11]);
            float s67 = (s[12] + s[13]) + (s[14] + s[15]);
            float lsum = (s01 + s23) + (s45 + s67);
            lsum += __shfl_xor(lsum, 32);
            lrun += lsum;
        }
        unsigned wv[8];
        #pragma unroll
        for (int i = 0; i < 8; ++i)
            asm("v_cvt_pk_bf16_f32 %0, %1, %2" : "=v"(wv[i]) : "v"(s[2 * i]), "v"(s[2 * i + 1]));
        unsigned p00 = wv[0], p02 = wv[2];
        unsigned p01 = wv[1], p03 = wv[3];
        unsigned p10 = wv[4], p12 = wv[6];
        unsigned p11 = wv[5], p13 = wv[7];
        asm("v_permlane32_swap_b32 %0, %1" : "+v"(p00), "+v"(p02));
        asm("v_permlane32_swap_b32 %0, %1" : "+v"(p01), "+v"(p03));
        asm("v_permlane32_swap_b32 %0, %1" : "+v"(p10), "+v"(p12));
        asm("v_permlane32_swap_b32 %0, %1" : "+v"(p11), "+v"(p13));
        u32x4 pb0u = {p00, p01, p02, p03};
        u32x4 pb1u = {p10, p11, p12, p13};
        bf16x8 pb0, pb1;
        __builtin_memcpy(&pb0, &pb0u, 16);
        __builtin_memcpy(&pb1, &pb1u, 16);
        __builtin_amdgcn_s_setprio(1);
        o0 = __builtin_amdgcn_mfma_f32_32x32x16_bf16(vf00, pb0, o0, 0, 0, 0);
        o0 = __builtin_amdgcn_mfma_f32_32x32x16_bf16(vf01, pb1, o0, 0, 0, 0);
        o1 = __builtin_amdgcn_mfma_f32_32x32x16_bf16(vf10, pb0, o1, 0, 0, 0);
        o1 = __builtin_amdgcn_mfma_f32_32x32x16_bf16(vf11, pb1, o1, 0, 0, 0);
        __builtin_amdgcn_s_setprio(0);
    }

    #pragma unroll
    for (int r = 0; r < 16; ++r) {
        const int h = (r & 3) + 8 * (r >> 2) + 4 * hi;
        Op[w][l31][h]      = o0[r];
        Op[w][l31][32 + h] = o1[r];
    }
    if (hi == 0) {
        Ml[w][l31][0] = mrun;
        Ml[w][l31][1] = lrun;
    }
    __syncthreads();

    {
        const bool tb   = (w >= 4);
        const int  base = tb ? WA : 0;
        const int  cnt  = tb ? WB : WA;
        const long oq0  = (long)(tb ? stB : stA) * 32;
        #pragma unroll
        for (int rr = 0; rr < 8; ++rr) {
            const int row = (w & 3) * 8 + rr;
            float M = -1e30f;
            for (int j = 0; j < cnt; ++j)
                M = fmaxf(M, Ml[base + j][row][0]);
            float Ls = 0.f, val = 0.f;
            for (int j = 0; j < cnt; ++j) {
                const float a = fexp2(Ml[base + j][row][0] - M);
                Ls  += a * Ml[base + j][row][1];
                val += a * Op[base + j][row][L];
            }
            out[((long)b * TT + oq0 + row) * 64 + L] = val / Ls;
        }
    }
}

extern "C" void kernel_launch(void* const* d_in, const int* in_sizes, int n_in,
                              void* d_out, int out_size, void* d_ws, size_t ws_size,
                              hipStream_t stream)
{
    const float* x  = (const float*)d_in[0];
    const float* Wq = (const float*)d_in[1];
    const float* Wk = (const float*)d_in[2];
    const float* Wv = (const float*)d_in[3];
    float* out = (float*)d_out;

    const size_t n = (size_t)BB * TT * H;   // 1,048,576 per tensor
    short* q  = (short*)d_ws;
    short* k  = q + n;
    short* vt = k + n;                      // V transposed: [B][H][T]
    short* Wb = vt + n;                     // 196,608 shorts

    // dummy regions for ablation kernels (ws is >=268 MB; real data <8 MB)
    short* dummy  = (short*)((char*)d_ws + (64u << 20));   // 32 MB used
    short* dummy2 = (short*)((char*)d_ws + (128u << 20));  // 6 MB used

    // ---- real pipeline (unchanged, runs first) ----
    pack_w  <<<dim3(96),  256, 0, stream>>>(Wq, Wk, Wv, Wb);
    proj_v5 <<<dim3(256), 256, 0, stream>>>(x, Wb, q, k, vt);
    attn_v8 <<<dim3(256), 512, 0, stream>>>(q, k, vt, out);

    // ---- ablation probes (outputs to dummy; after real pipeline) ----
    abl_copy<<<dim3(2048), 256, 0, stream>>>(x, dummy);
    abl_comp<<<dim3(256),  256, 0, stream>>>(Wb, dummy2, dummy2 + n, dummy2 + 2 * n);
}

// Round 15
// 65.232 us; speedup vs baseline: 2.3658x; 2.3658x over previous
//
#include <hip/hip_runtime.h>

#define E  1024
#define H  64
#define BB 8
#define TT 2048

typedef __attribute__((ext_vector_type(8)))  short bf16x8;
typedef __attribute__((ext_vector_type(4)))  float f32x4;
typedef __attribute__((ext_vector_type(16))) float f32x16;
typedef __attribute__((ext_vector_type(8)))  short short8;
typedef __attribute__((ext_vector_type(4)))  short short4v;
typedef __attribute__((ext_vector_type(4)))  unsigned u32x4;

__device__ __forceinline__ short f2bf(float f) {
    union { float f; unsigned u; } v; v.f = f;
    unsigned r = v.u + 0x7FFFu + ((v.u >> 16) & 1u);   // RNE
    return (short)(r >> 16);
}

// fast 2^x via the HW transcendental (no HIP __exp2f intrinsic exists)
__device__ __forceinline__ float fexp2(float x) {
    float r;
    asm("v_exp_f32 %0, %1" : "=v"(r) : "v"(x));
    return r;
}

// 8 fp32 -> bf16x8 via 4x v_cvt_pk_bf16_f32
__device__ __forceinline__ bf16x8 cvt8(float4 a0, float4 a1) {
    unsigned w0, w1, w2, w3;
    asm("v_cvt_pk_bf16_f32 %0, %1, %2" : "=v"(w0) : "v"(a0.x), "v"(a0.y));
    asm("v_cvt_pk_bf16_f32 %0, %1, %2" : "=v"(w1) : "v"(a0.z), "v"(a0.w));
    asm("v_cvt_pk_bf16_f32 %0, %1, %2" : "=v"(w2) : "v"(a1.x), "v"(a1.y));
    asm("v_cvt_pk_bf16_f32 %0, %1, %2" : "=v"(w3) : "v"(a1.z), "v"(a1.w));
    u32x4 u = {w0, w1, w2, w3};
    bf16x8 r;
    __builtin_memcpy(&r, &u, 16);
    return r;
}

// ---- pack W into B-fragment layout for mfma_f32_32x32x16_bf16 ----
// Wb2[((kc*6 + f)*64 + l)*8 + j] = bf16( W_m[(kc*16 + (l>>5)*8 + j)][n&63] )
// where n = f*32 + (l&31), m = n>>6 selects Wq/Wk/Wv.
__global__ __launch_bounds__(256)
void pack_w2(const float* __restrict__ Wq, const float* __restrict__ Wk,
             const float* __restrict__ Wv, short* __restrict__ Wb2)
{
    const int t  = blockIdx.x * 256 + threadIdx.x;   // 24576 total
    const int l  = t & 63;
    const int fg = (t >> 6) % 6;                     // frag 0..5
    const int kc = t / 384;                          // K16-chunk 0..63
    const int n  = fg * 32 + (l & 31);
    const int m  = n >> 6, nn = n & 63;
    const float* W = (m == 0) ? Wq : (m == 1 ? Wk : Wv);
    const int e0 = kc * 16 + ((l >> 5) << 3);
    short8 o;
    #pragma unroll
    for (int j = 0; j < 8; ++j) o[j] = f2bf(W[(e0 + j) * 64 + nn]);
    *(short8*)&Wb2[(size_t)t * 8] = o;
}

// ---- proj v7: attn_v8-shaped loop. 32x32x16 MFMA, frags from global ----
// grid 512 x 512 thr (2 blocks/CU, 4 waves/SIMD). Block = one 32-row tile.
// Wave (cg, ks): col-group cg (3 frags = 96 cols), K-split ks (K=256, 16
// steps). Per step: 2 float4 x loads (32B/lane, direct) + cvt8 + 3 B-frag
// 16B loads (L2) + 3 MFMA 32x32 (48 issue-cyc per load dependency).
// Merge: ks=1..3 publish via transposed scalar LDS (conflict-free), ks=0
// reduces + stores. No LDS in the K-loop.
__global__ __launch_bounds__(512)
void proj_v7(const float* __restrict__ x, const short* __restrict__ Wb2,
             short* __restrict__ q, short* __restrict__ k, short* __restrict__ vt)
{
    __shared__ float part[2][3][3][16][64];   // 72 KB
    const int t  = threadIdx.x;
    const int l  = t & 63;
    const int w  = t >> 6;
    const int cg = w & 1, ks = w >> 1;        // col-group, K-split
    const int l31 = l & 31, hi = l >> 5;
    const long row0 = (long)blockIdx.x * 32;

    f32x16 acc0 = {}, acc1 = {}, acc2 = {};

    const float* xp = x + (row0 + l31) * E + ks * 256 + hi * 8;
    const short* wb = Wb2 + ((size_t)(ks * 16 * 6 + cg * 3) * 64 + l) * 8;

    #pragma unroll 4
    for (int s = 0; s < 16; ++s) {
        float4 a0 = *(const float4*)(xp + s * 16);
        float4 a1 = *(const float4*)(xp + s * 16 + 4);
        bf16x8 af = cvt8(a0, a1);
        const short* wp = wb + (size_t)s * 6 * 512;
        bf16x8 b0 = *(const bf16x8*)(wp);
        bf16x8 b1 = *(const bf16x8*)(wp + 512);
        bf16x8 b2 = *(const bf16x8*)(wp + 1024);
        acc0 = __builtin_amdgcn_mfma_f32_32x32x16_bf16(af, b0, acc0, 0, 0, 0);
        acc1 = __builtin_amdgcn_mfma_f32_32x32x16_bf16(af, b1, acc1, 0, 0, 0);
        acc2 = __builtin_amdgcn_mfma_f32_32x32x16_bf16(af, b2, acc2, 0, 0, 0);
    }

    if (ks != 0) {
        #pragma unroll
        for (int i = 0; i < 16; ++i) {
            part[cg][ks - 1][0][i][l] = acc0[i];
            part[cg][ks - 1][1][i][l] = acc1[i];
            part[cg][ks - 1][2][i][l] = acc2[i];
        }
    }
    __syncthreads();
    if (ks == 0) {
        #pragma unroll
        for (int i = 0; i < 16; ++i) {
            acc0[i] += part[cg][0][0][i][l] + part[cg][1][0][i][l] + part[cg][2][0][i][l];
            acc1[i] += part[cg][0][1][i][l] + part[cg][1][1][i][l] + part[cg][2][1][i][l];
            acc2[i] += part[cg][0][2][i][l] + part[cg][1][2][i][l] + part[cg][2][2][i][l];
        }
        const long bb = row0 >> 11;
        const int  tbase = (int)(row0 & 2047);
        #pragma unroll
        for (int f = 0; f < 3; ++f) {
            const f32x16 acc = (f == 0) ? acc0 : (f == 1) ? acc1 : acc2;
            const int n = cg * 96 + f * 32 + l31;
            const int m = n >> 6;
            const int h = n & 63;
            if (m == 2) {
                // Vt[b][h][t]: regs 4a..4a+3 -> rows 8a+4hi+{0..3} (consecutive)
                #pragma unroll
                for (int a = 0; a < 4; ++a) {
                    short4v pkt;
                    #pragma unroll
                    for (int r = 0; r < 4; ++r) pkt[r] = f2bf(acc[a * 4 + r]);
                    *(short4v*)&vt[(bb * 64 + h) * TT + tbase + a * 8 + hi * 4] = pkt;
                }
            } else {
                short* base = (m == 0) ? q : k;
                // fold 1/sqrt(H) AND log2(e) into q -> softmax uses exp2
                const float sc = (m == 0) ? (0.125f * 1.44269504f) : 1.0f;
                #pragma unroll
                for (int r = 0; r < 16; ++r) {
                    const int crow = (r & 3) + 8 * (r >> 2) + 4 * hi;
                    base[(row0 + crow) * 64 + h] = f2bf(acc[r] * sc);
                }
            }
        }
    }
}

// ---- 32x32 swapped-QK^T flash attention (unchanged) ----
__global__ __launch_bounds__(512)
void attn_v8(const short* __restrict__ qg,
             const short* __restrict__ kg,
             const short* __restrict__ vtg,
             float* __restrict__ out)
{
    __shared__ float Op[8][32][66];
    __shared__ float Ml[8][32][2];

    const int t   = threadIdx.x;
    const int L   = t & 63;
    const int w   = t >> 6;
    const int bid = blockIdx.x;
    const int b   = bid & 7;
    const int pr  = bid >> 3;
    const int l31 = L & 31, hi = L >> 5;

    const int stA = pr, stB = 63 - pr;
    const int nA = stA + 1;
    int WA = (8 * nA + 32) / 65;
    WA = WA < 1 ? 1 : (WA > 7 ? 7 : WA);
    const int WB = 8 - WA;

    const bool isB  = (w >= WA);
    const int  st   = isB ? stB : stA;
    const int  q0   = st * 32;
    const int  strd = isB ? WB : WA;
    const int  c0   = isB ? (w - WA) : w;

    bf16x8 qf[4];
    {
        const short* qp = qg + ((long)b * TT + q0 + l31) * 64 + hi * 8;
        qf[0] = *(const bf16x8*)(qp);
        qf[1] = *(const bf16x8*)(qp + 16);
        qf[2] = *(const bf16x8*)(qp + 32);
        qf[3] = *(const bf16x8*)(qp + 48);
    }

    f32x16 o0 = {}, o1 = {};
    float mrun = -1e30f, lrun = 0.f;

    const short* kbase = kg  + ((long)b * TT + l31) * 64 + hi * 8;
    const short* vbase = vtg + ((long)b * 64 + l31) * TT + hi * 8;

    for (int ci = c0; ci <= st; ci += strd) {
        const int kvs = ci * 32;
        const short* kp = kbase + (long)kvs * 64;
        bf16x8 kf0 = *(const bf16x8*)(kp);
        bf16x8 kf1 = *(const bf16x8*)(kp + 16);
        bf16x8 kf2 = *(const bf16x8*)(kp + 32);
        bf16x8 kf3 = *(const bf16x8*)(kp + 48);
        const short* vp = vbase + kvs;
        bf16x8 vf00 = *(const bf16x8*)(vp);
        bf16x8 vf01 = *(const bf16x8*)(vp + 16);
        bf16x8 vf10 = *(const bf16x8*)(vp + 32 * TT);
        bf16x8 vf11 = *(const bf16x8*)(vp + 32 * TT + 16);

        f32x16 s = {};
        __builtin_amdgcn_s_setprio(1);
        s = __builtin_amdgcn_mfma_f32_32x32x16_bf16(kf0, qf[0], s, 0, 0, 0);
        s = __builtin_amdgcn_mfma_f32_32x32x16_bf16(kf1, qf[1], s, 0, 0, 0);
        s = __builtin_amdgcn_mfma_f32_32x32x16_bf16(kf2, qf[2], s, 0, 0, 0);
        s = __builtin_amdgcn_mfma_f32_32x32x16_bf16(kf3, qf[3], s, 0, 0, 0);
        __builtin_amdgcn_s_setprio(0);

        if (kvs == q0) {
            #pragma unroll
            for (int r = 0; r < 16; ++r) {
                const int crow = (r & 3) + 8 * (r >> 2) + 4 * hi;
                if (crow > l31) s[r] = -1e30f;
            }
        }
        float m01 = fmaxf(s[0], s[1]),   m23 = fmaxf(s[2], s[3]);
        float m45 = fmaxf(s[4], s[5]),   m67 = fmaxf(s[6], s[7]);
        float m89 = fmaxf(s[8], s[9]),   mab = fmaxf(s[10], s[11]);
        float mcd = fmaxf(s[12], s[13]), mef = fmaxf(s[14], s[15]);
        float mloc = fmaxf(fmaxf(fmaxf(m01, m23), fmaxf(m45, m67)),
                           fmaxf(fmaxf(m89, mab), fmaxf(mcd, mef)));
        mloc = fmaxf(mloc, __shfl_xor(mloc, 32));
        if (__any(mloc > mrun + 8.f)) {
            const float mnew = fmaxf(mrun, mloc);
            const float a = fexp2(mrun - mnew);
            mrun = mnew;
            lrun *= a;
            #pragma unroll
            for (int r = 0; r < 16; ++r) { o0[r] *= a; o1[r] *= a; }
        }
        #pragma unroll
        for (int r = 0; r < 16; ++r) s[r] = fexp2(s[r] - mrun);
        {
            float s01 = (s[0] + s[1]) + (s[2] + s[3]);
            float s23 = (s[4] + s[5]) + (s[6] + s[7]);
            float s45 = (s[8] + s[9]) + (s[10] + s[11]);
            float s67 = (s[12] + s[13]) + (s[14] + s[15]);
            float lsum = (s01 + s23) + (s45 + s67);
            lsum += __shfl_xor(lsum, 32);
            lrun += lsum;
        }
        unsigned wv[8];
        #pragma unroll
        for (int i = 0; i < 8; ++i)
            asm("v_cvt_pk_bf16_f32 %0, %1, %2" : "=v"(wv[i]) : "v"(s[2 * i]), "v"(s[2 * i + 1]));
        unsigned p00 = wv[0], p02 = wv[2];
        unsigned p01 = wv[1], p03 = wv[3];
        unsigned p10 = wv[4], p12 = wv[6];
        unsigned p11 = wv[5], p13 = wv[7];
        asm("v_permlane32_swap_b32 %0, %1" : "+v"(p00), "+v"(p02));
        asm("v_permlane32_swap_b32 %0, %1" : "+v"(p01), "+v"(p03));
        asm("v_permlane32_swap_b32 %0, %1" : "+v"(p10), "+v"(p12));
        asm("v_permlane32_swap_b32 %0, %1" : "+v"(p11), "+v"(p13));
        u32x4 pb0u = {p00, p01, p02, p03};
        u32x4 pb1u = {p10, p11, p12, p13};
        bf16x8 pb0, pb1;
        __builtin_memcpy(&pb0, &pb0u, 16);
        __builtin_memcpy(&pb1, &pb1u, 16);
        __builtin_amdgcn_s_setprio(1);
        o0 = __builtin_amdgcn_mfma_f32_32x32x16_bf16(vf00, pb0, o0, 0, 0, 0);
        o0 = __builtin_amdgcn_mfma_f32_32x32x16_bf16(vf01, pb1, o0, 0, 0, 0);
        o1 = __builtin_amdgcn_mfma_f32_32x32x16_bf16(vf10, pb0, o1, 0, 0, 0);
        o1 = __builtin_amdgcn_mfma_f32_32x32x16_bf16(vf11, pb1, o1, 0, 0, 0);
        __builtin_amdgcn_s_setprio(0);
    }

    #pragma unroll
    for (int r = 0; r < 16; ++r) {
        const int h = (r & 3) + 8 * (r >> 2) + 4 * hi;
        Op[w][l31][h]      = o0[r];
        Op[w][l31][32 + h] = o1[r];
    }
    if (hi == 0) {
        Ml[w][l31][0] = mrun;
        Ml[w][l31][1] = lrun;
    }
    __syncthreads();

    {
        const bool tb   = (w >= 4);
        const int  base = tb ? WA : 0;
        const int  cnt  = tb ? WB : WA;
        const long oq0  = (long)(tb ? stB : stA) * 32;
        #pragma unroll
        for (int rr = 0; rr < 8; ++rr) {
            const int row = (w & 3) * 8 + rr;
            float M = -1e30f;
            for (int j = 0; j < cnt; ++j)
                M = fmaxf(M, Ml[base + j][row][0]);
            float Ls = 0.f, val = 0.f;
            for (int j = 0; j < cnt; ++j) {
                const float a = fexp2(Ml[base + j][row][0] - M);
                Ls  += a * Ml[base + j][row][1];
                val += a * Op[base + j][row][L];
            }
            out[((long)b * TT + oq0 + row) * 64 + L] = val / Ls;
        }
    }
}

extern "C" void kernel_launch(void* const* d_in, const int* in_sizes, int n_in,
                              void* d_out, int out_size, void* d_ws, size_t ws_size,
                              hipStream_t stream)
{
    const float* x  = (const float*)d_in[0];
    const float* Wq = (const float*)d_in[1];
    const float* Wk = (const float*)d_in[2];
    const float* Wv = (const float*)d_in[3];
    float* out = (float*)d_out;

    const size_t n = (size_t)BB * TT * H;   // 1,048,576 per tensor
    short* q   = (short*)d_ws;
    short* k   = q + n;
    short* vt  = k + n;                     // V transposed: [B][H][T]
    short* Wb2 = vt + n;                    // 196,608 shorts

    pack_w2 <<<dim3(96),  256, 0, stream>>>(Wq, Wk, Wv, Wb2);
    proj_v7 <<<dim3(512), 512, 0, stream>>>(x, Wb2, q, k, vt);
    attn_v8 <<<dim3(256), 512, 0, stream>>>(q, k, vt, out);
}

// Round 16
// 61.443 us; speedup vs baseline: 2.5117x; 1.0617x over previous
//
#include <hip/hip_runtime.h>

#define E  1024
#define H  64
#define BB 8
#define TT 2048

typedef __attribute__((ext_vector_type(8)))  short bf16x8;
typedef __attribute__((ext_vector_type(4)))  float f32x4;
typedef __attribute__((ext_vector_type(16))) float f32x16;
typedef __attribute__((ext_vector_type(8)))  short short8;
typedef __attribute__((ext_vector_type(4)))  short short4v;
typedef __attribute__((ext_vector_type(4)))  unsigned u32x4;

__device__ __forceinline__ short f2bf(float f) {
    union { float f; unsigned u; } v; v.f = f;
    unsigned r = v.u + 0x7FFFu + ((v.u >> 16) & 1u);   // RNE
    return (short)(r >> 16);
}

// fast 2^x via the HW transcendental (no HIP __exp2f intrinsic exists)
__device__ __forceinline__ float fexp2(float x) {
    float r;
    asm("v_exp_f32 %0, %1" : "=v"(r) : "v"(x));
    return r;
}

// 8 fp32 -> bf16x8 via 4x v_cvt_pk_bf16_f32
__device__ __forceinline__ bf16x8 cvt8(float4 a0, float4 a1) {
    unsigned w0, w1, w2, w3;
    asm("v_cvt_pk_bf16_f32 %0, %1, %2" : "=v"(w0) : "v"(a0.x), "v"(a0.y));
    asm("v_cvt_pk_bf16_f32 %0, %1, %2" : "=v"(w1) : "v"(a0.z), "v"(a0.w));
    asm("v_cvt_pk_bf16_f32 %0, %1, %2" : "=v"(w2) : "v"(a1.x), "v"(a1.y));
    asm("v_cvt_pk_bf16_f32 %0, %1, %2" : "=v"(w3) : "v"(a1.z), "v"(a1.w));
    u32x4 u = {w0, w1, w2, w3};
    bf16x8 r;
    __builtin_memcpy(&r, &u, 16);
    return r;
}

// ---- pack W into B-fragment layout for mfma_f32_32x32x16_bf16 ----
__global__ __launch_bounds__(256)
void pack_w2(const float* __restrict__ Wq, const float* __restrict__ Wk,
             const float* __restrict__ Wv, short* __restrict__ Wb2)
{
    const int t  = blockIdx.x * 256 + threadIdx.x;   // 24576 total
    const int l  = t & 63;
    const int fg = (t >> 6) % 6;                     // frag 0..5
    const int kc = t / 384;                          // K16-chunk 0..63
    const int n  = fg * 32 + (l & 31);
    const int m  = n >> 6, nn = n & 63;
    const float* W = (m == 0) ? Wq : (m == 1 ? Wk : Wv);
    const int e0 = kc * 16 + ((l >> 5) << 3);
    short8 o;
    #pragma unroll
    for (int j = 0; j < 8; ++j) o[j] = f2bf(W[(e0 + j) * 64 + nn]);
    *(short8*)&Wb2[(size_t)t * 8] = o;
}

// ---- proj v8: v7 + register headroom + explicit 2-deep operand dbuf ----
// __launch_bounds__(512,2) gives ~128 VGPR (v7's 72-VGPR starvation forced
// load->vmcnt(0)->MFMA serialization each step). Named A/B operand sets,
// stage s+1's 5 loads issued before stage s's MFMAs -> ~10 loads in flight.
__global__ __launch_bounds__(512, 2)
void proj_v8(const float* __restrict__ x, const short* __restrict__ Wb2,
             short* __restrict__ q, short* __restrict__ k, short* __restrict__ vt)
{
    __shared__ float part[2][3][3][16][64];   // 72 KB
    const int t  = threadIdx.x;
    const int l  = t & 63;
    const int w  = t >> 6;
    const int cg = w & 1, ks = w >> 1;        // col-group, K-split
    const int l31 = l & 31, hi = l >> 5;
    const long row0 = (long)blockIdx.x * 32;

    f32x16 acc0 = {}, acc1 = {}, acc2 = {};

    const float* xp = x + (row0 + l31) * E + ks * 256 + hi * 8;
    const short* wb = Wb2 + ((size_t)(ks * 16 * 6 + cg * 3) * 64 + l) * 8;
    const size_t WSTEP = 6 * 512;

    // ---- prologue: stage A <- step 0 ----
    float4 xa0A = *(const float4*)(xp);
    float4 xa1A = *(const float4*)(xp + 4);
    bf16x8 b0A = *(const bf16x8*)(wb);
    bf16x8 b1A = *(const bf16x8*)(wb + 512);
    bf16x8 b2A = *(const bf16x8*)(wb + 1024);

    float4 xa0B, xa1B;
    bf16x8 b0B, b1B, b2B;

    #pragma unroll
    for (int s = 0; s < 16; s += 2) {
        // issue stage B (step s+1) loads before consuming stage A
        {
            const float* xn = xp + (s + 1) * 16;
            xa0B = *(const float4*)(xn);
            xa1B = *(const float4*)(xn + 4);
            const short* wn = wb + (size_t)(s + 1) * WSTEP;
            b0B = *(const bf16x8*)(wn);
            b1B = *(const bf16x8*)(wn + 512);
            b2B = *(const bf16x8*)(wn + 1024);
        }
        {
            bf16x8 af = cvt8(xa0A, xa1A);
            acc0 = __builtin_amdgcn_mfma_f32_32x32x16_bf16(af, b0A, acc0, 0, 0, 0);
            acc1 = __builtin_amdgcn_mfma_f32_32x32x16_bf16(af, b1A, acc1, 0, 0, 0);
            acc2 = __builtin_amdgcn_mfma_f32_32x32x16_bf16(af, b2A, acc2, 0, 0, 0);
        }
        // issue stage A (step s+2) loads before consuming stage B
        if (s + 2 < 16) {
            const float* xn = xp + (s + 2) * 16;
            xa0A = *(const float4*)(xn);
            xa1A = *(const float4*)(xn + 4);
            const short* wn = wb + (size_t)(s + 2) * WSTEP;
            b0A = *(const bf16x8*)(wn);
            b1A = *(const bf16x8*)(wn + 512);
            b2A = *(const bf16x8*)(wn + 1024);
        }
        {
            bf16x8 af = cvt8(xa0B, xa1B);
            acc0 = __builtin_amdgcn_mfma_f32_32x32x16_bf16(af, b0B, acc0, 0, 0, 0);
            acc1 = __builtin_amdgcn_mfma_f32_32x32x16_bf16(af, b1B, acc1, 0, 0, 0);
            acc2 = __builtin_amdgcn_mfma_f32_32x32x16_bf16(af, b2B, acc2, 0, 0, 0);
        }
    }

    if (ks != 0) {
        #pragma unroll
        for (int i = 0; i < 16; ++i) {
            part[cg][ks - 1][0][i][l] = acc0[i];
            part[cg][ks - 1][1][i][l] = acc1[i];
            part[cg][ks - 1][2][i][l] = acc2[i];
        }
    }
    __syncthreads();
    if (ks == 0) {
        #pragma unroll
        for (int i = 0; i < 16; ++i) {
            acc0[i] += part[cg][0][0][i][l] + part[cg][1][0][i][l] + part[cg][2][0][i][l];
            acc1[i] += part[cg][0][1][i][l] + part[cg][1][1][i][l] + part[cg][2][1][i][l];
            acc2[i] += part[cg][0][2][i][l] + part[cg][1][2][i][l] + part[cg][2][2][i][l];
        }
        const long bb = row0 >> 11;
        const int  tbase = (int)(row0 & 2047);
        #pragma unroll
        for (int f = 0; f < 3; ++f) {
            const f32x16 acc = (f == 0) ? acc0 : (f == 1) ? acc1 : acc2;
            const int n = cg * 96 + f * 32 + l31;
            const int m = n >> 6;
            const int h = n & 63;
            if (m == 2) {
                #pragma unroll
                for (int a = 0; a < 4; ++a) {
                    short4v pkt;
                    #pragma unroll
                    for (int r = 0; r < 4; ++r) pkt[r] = f2bf(acc[a * 4 + r]);
                    *(short4v*)&vt[(bb * 64 + h) * TT + tbase + a * 8 + hi * 4] = pkt;
                }
            } else {
                short* base = (m == 0) ? q : k;
                // fold 1/sqrt(H) AND log2(e) into q -> softmax uses exp2
                const float sc = (m == 0) ? (0.125f * 1.44269504f) : 1.0f;
                #pragma unroll
                for (int r = 0; r < 16; ++r) {
                    const int crow = (r & 3) + 8 * (r >> 2) + 4 * hi;
                    base[(row0 + crow) * 64 + h] = f2bf(acc[r] * sc);
                }
            }
        }
    }
}

// ---- 32x32 swapped-QK^T flash attention (unchanged) ----
__global__ __launch_bounds__(512)
void attn_v8(const short* __restrict__ qg,
             const short* __restrict__ kg,
             const short* __restrict__ vtg,
             float* __restrict__ out)
{
    __shared__ float Op[8][32][66];
    __shared__ float Ml[8][32][2];

    const int t   = threadIdx.x;
    const int L   = t & 63;
    const int w   = t >> 6;
    const int bid = blockIdx.x;
    const int b   = bid & 7;
    const int pr  = bid >> 3;
    const int l31 = L & 31, hi = L >> 5;

    const int stA = pr, stB = 63 - pr;
    const int nA = stA + 1;
    int WA = (8 * nA + 32) / 65;
    WA = WA < 1 ? 1 : (WA > 7 ? 7 : WA);
    const int WB = 8 - WA;

    const bool isB  = (w >= WA);
    const int  st   = isB ? stB : stA;
    const int  q0   = st * 32;
    const int  strd = isB ? WB : WA;
    const int  c0   = isB ? (w - WA) : w;

    bf16x8 qf[4];
    {
        const short* qp = qg + ((long)b * TT + q0 + l31) * 64 + hi * 8;
        qf[0] = *(const bf16x8*)(qp);
        qf[1] = *(const bf16x8*)(qp + 16);
        qf[2] = *(const bf16x8*)(qp + 32);
        qf[3] = *(const bf16x8*)(qp + 48);
    }

    f32x16 o0 = {}, o1 = {};
    float mrun = -1e30f, lrun = 0.f;

    const short* kbase = kg  + ((long)b * TT + l31) * 64 + hi * 8;
    const short* vbase = vtg + ((long)b * 64 + l31) * TT + hi * 8;

    for (int ci = c0; ci <= st; ci += strd) {
        const int kvs = ci * 32;
        const short* kp = kbase + (long)kvs * 64;
        bf16x8 kf0 = *(const bf16x8*)(kp);
        bf16x8 kf1 = *(const bf16x8*)(kp + 16);
        bf16x8 kf2 = *(const bf16x8*)(kp + 32);
        bf16x8 kf3 = *(const bf16x8*)(kp + 48);
        const short* vp = vbase + kvs;
        bf16x8 vf00 = *(const bf16x8*)(vp);
        bf16x8 vf01 = *(const bf16x8*)(vp + 16);
        bf16x8 vf10 = *(const bf16x8*)(vp + 32 * TT);
        bf16x8 vf11 = *(const bf16x8*)(vp + 32 * TT + 16);

        f32x16 s = {};
        __builtin_amdgcn_s_setprio(1);
        s = __builtin_amdgcn_mfma_f32_32x32x16_bf16(kf0, qf[0], s, 0, 0, 0);
        s = __builtin_amdgcn_mfma_f32_32x32x16_bf16(kf1, qf[1], s, 0, 0, 0);
        s = __builtin_amdgcn_mfma_f32_32x32x16_bf16(kf2, qf[2], s, 0, 0, 0);
        s = __builtin_amdgcn_mfma_f32_32x32x16_bf16(kf3, qf[3], s, 0, 0, 0);
        __builtin_amdgcn_s_setprio(0);

        if (kvs == q0) {
            #pragma unroll
            for (int r = 0; r < 16; ++r) {
                const int crow = (r & 3) + 8 * (r >> 2) + 4 * hi;
                if (crow > l31) s[r] = -1e30f;
            }
        }
        float m01 = fmaxf(s[0], s[1]),   m23 = fmaxf(s[2], s[3]);
        float m45 = fmaxf(s[4], s[5]),   m67 = fmaxf(s[6], s[7]);
        float m89 = fmaxf(s[8], s[9]),   mab = fmaxf(s[10], s[11]);
        float mcd = fmaxf(s[12], s[13]), mef = fmaxf(s[14], s[15]);
        float mloc = fmaxf(fmaxf(fmaxf(m01, m23), fmaxf(m45, m67)),
                           fmaxf(fmaxf(m89, mab), fmaxf(mcd, mef)));
        mloc = fmaxf(mloc, __shfl_xor(mloc, 32));
        if (__any(mloc > mrun + 8.f)) {
            const float mnew = fmaxf(mrun, mloc);
            const float a = fexp2(mrun - mnew);
            mrun = mnew;
            lrun *= a;
            #pragma unroll
            for (int r = 0; r < 16; ++r) { o0[r] *= a; o1[r] *= a; }
        }
        #pragma unroll
        for (int r = 0; r < 16; ++r) s[r] = fexp2(s[r] - mrun);
        {
            float s01 = (s[0] + s[1]) + (s[2] + s[3]);
            float s23 = (s[4] + s[5]) + (s[6] + s[7]);
            float s45 = (s[8] + s[9]) + (s[10] + s[11]);
            float s67 = (s[12] + s[13]) + (s[14] + s[15]);
            float lsum = (s01 + s23) + (s45 + s67);
            lsum += __shfl_xor(lsum, 32);
            lrun += lsum;
        }
        unsigned wv[8];
        #pragma unroll
        for (int i = 0; i < 8; ++i)
            asm("v_cvt_pk_bf16_f32 %0, %1, %2" : "=v"(wv[i]) : "v"(s[2 * i]), "v"(s[2 * i + 1]));
        unsigned p00 = wv[0], p02 = wv[2];
        unsigned p01 = wv[1], p03 = wv[3];
        unsigned p10 = wv[4], p12 = wv[6];
        unsigned p11 = wv[5], p13 = wv[7];
        asm("v_permlane32_swap_b32 %0, %1" : "+v"(p00), "+v"(p02));
        asm("v_permlane32_swap_b32 %0, %1" : "+v"(p01), "+v"(p03));
        asm("v_permlane32_swap_b32 %0, %1" : "+v"(p10), "+v"(p12));
        asm("v_permlane32_swap_b32 %0, %1" : "+v"(p11), "+v"(p13));
        u32x4 pb0u = {p00, p01, p02, p03};
        u32x4 pb1u = {p10, p11, p12, p13};
        bf16x8 pb0, pb1;
        __builtin_memcpy(&pb0, &pb0u, 16);
        __builtin_memcpy(&pb1, &pb1u, 16);
        __builtin_amdgcn_s_setprio(1);
        o0 = __builtin_amdgcn_mfma_f32_32x32x16_bf16(vf00, pb0, o0, 0, 0, 0);
        o0 = __builtin_amdgcn_mfma_f32_32x32x16_bf16(vf01, pb1, o0, 0, 0, 0);
        o1 = __builtin_amdgcn_mfma_f32_32x32x16_bf16(vf10, pb0, o1, 0, 0, 0);
        o1 = __builtin_amdgcn_mfma_f32_32x32x16_bf16(vf11, pb1, o1, 0, 0, 0);
        __builtin_amdgcn_s_setprio(0);
    }

    #pragma unroll
    for (int r = 0; r < 16; ++r) {
        const int h = (r & 3) + 8 * (r >> 2) + 4 * hi;
        Op[w][l31][h]      = o0[r];
        Op[w][l31][32 + h] = o1[r];
    }
    if (hi == 0) {
        Ml[w][l31][0] = mrun;
        Ml[w][l31][1] = lrun;
    }
    __syncthreads();

    {
        const bool tb   = (w >= 4);
        const int  base = tb ? WA : 0;
        const int  cnt  = tb ? WB : WA;
        const long oq0  = (long)(tb ? stB : stA) * 32;
        #pragma unroll
        for (int rr = 0; rr < 8; ++rr) {
            const int row = (w & 3) * 8 + rr;
            float M = -1e30f;
            for (int j = 0; j < cnt; ++j)
                M = fmaxf(M, Ml[base + j][row][0]);
            float Ls = 0.f, val = 0.f;
            for (int j = 0; j < cnt; ++j) {
                const float a = fexp2(Ml[base + j][row][0] - M);
                Ls  += a * Ml[base + j][row][1];
                val += a * Op[base + j][row][L];
            }
            out[((long)b * TT + oq0 + row) * 64 + L] = val / Ls;
        }
    }
}

extern "C" void kernel_launch(void* const* d_in, const int* in_sizes, int n_in,
                              void* d_out, int out_size, void* d_ws, size_t ws_size,
                              hipStream_t stream)
{
    const float* x  = (const float*)d_in[0];
    const float* Wq = (const float*)d_in[1];
    const float* Wk = (const float*)d_in[2];
    const float* Wv = (const float*)d_in[3];
    float* out = (float*)d_out;

    const size_t n = (size_t)BB * TT * H;   // 1,048,576 per tensor
    short* q   = (short*)d_ws;
    short* k   = q + n;
    short* vt  = k + n;                     // V transposed: [B][H][T]
    short* Wb2 = vt + n;                    // 196,608 shorts

    pack_w2 <<<dim3(96),  256, 0, stream>>>(Wq, Wk, Wv, Wb2);
    proj_v8 <<<dim3(512), 512, 0, stream>>>(x, Wb2, q, k, vt);
    attn_v8 <<<dim3(256), 512, 0, stream>>>(q, k, vt, out);
}

// Round 17
// 51.954 us; speedup vs baseline: 2.9704x; 1.1826x over previous
//
#include <hip/hip_runtime.h>

#define E  1024
#define H  64
#define BB 8
#define TT 2048

typedef __attribute__((ext_vector_type(8)))  short bf16x8;
typedef __attribute__((ext_vector_type(4)))  float f32x4;
typedef __attribute__((ext_vector_type(16))) float f32x16;
typedef __attribute__((ext_vector_type(8)))  short short8;
typedef __attribute__((ext_vector_type(4)))  short short4v;
typedef __attribute__((ext_vector_type(4)))  unsigned u32x4;

__device__ __forceinline__ short f2bf(float f) {
    union { float f; unsigned u; } v; v.f = f;
    unsigned r = v.u + 0x7FFFu + ((v.u >> 16) & 1u);   // RNE
    return (short)(r >> 16);
}

// fast 2^x via the HW transcendental (no HIP __exp2f intrinsic exists)
__device__ __forceinline__ float fexp2(float x) {
    float r;
    asm("v_exp_f32 %0, %1" : "=v"(r) : "v"(x));
    return r;
}

// 8 fp32 -> bf16x8 via 4x v_cvt_pk_bf16_f32
__device__ __forceinline__ bf16x8 cvt8(float4 a0, float4 a1) {
    unsigned w0, w1, w2, w3;
    asm("v_cvt_pk_bf16_f32 %0, %1, %2" : "=v"(w0) : "v"(a0.x), "v"(a0.y));
    asm("v_cvt_pk_bf16_f32 %0, %1, %2" : "=v"(w1) : "v"(a0.z), "v"(a0.w));
    asm("v_cvt_pk_bf16_f32 %0, %1, %2" : "=v"(w2) : "v"(a1.x), "v"(a1.y));
    asm("v_cvt_pk_bf16_f32 %0, %1, %2" : "=v"(w3) : "v"(a1.z), "v"(a1.w));
    u32x4 u = {w0, w1, w2, w3};
    bf16x8 r;
    __builtin_memcpy(&r, &u, 16);
    return r;
}

// ---- pack W into per-K-step, frag-ordered CONTIGUOUS blocks (16x16x32 B) ----
// Wb3[(((s*2+kc)*12 + f)*64 + l)*8 + j] = bf16( W_m[k][n&63] )
//   k = (s*2+kc)*32 + (l>>4)*8 + j,  n = f*16 + (l&15),  m = n>>6.
// -> B tile for K-step s is one contiguous 24 KB block (linear LDS copy).
__global__ __launch_bounds__(256)
void pack_w3(const float* __restrict__ Wq, const float* __restrict__ Wk,
             const float* __restrict__ Wv, short* __restrict__ Wb3)
{
    const int t  = blockIdx.x * 256 + threadIdx.x;   // 24576 total
    const int l  = t & 63;
    const int f  = (t >> 6) % 12;
    const int sc = t / 768;                          // s*2+kc, 0..31
    const int n  = f * 16 + (l & 15);
    const int m  = n >> 6, nn = n & 63;
    const float* W = (m == 0) ? Wq : (m == 1 ? Wk : Wv);
    const int k0 = sc * 32 + ((l >> 4) << 3);
    short8 o;
    #pragma unroll
    for (int j = 0; j < 8; ++j) o[j] = f2bf(W[(k0 + j) * 64 + nn]);
    *(short8*)&Wb3[(size_t)t * 8] = o;
}

// ---- proj v9: m97-template GEMM — BOTH operands staged via global_load_lds ----
// BM=32, BN=192 (x read once), BK=64. grid 512 x 512 thr = 2 blocks/CU
// (blocks hide each other's barrier drains). Per K-step: stage A (fp32,
// source-XOR-swizzled 16B units -> conflict-free ds_read) + B (contiguous
// frag-ordered bf16) with 1+3 global_load_lds per thread -> barrier ->
// ds_read + cvt8 + 6 MFMA/wave -> barrier. No K-loop VGPR operands at all
// (bypasses the compiler's load-serialization seen in v7/v8).
__global__ __launch_bounds__(512)
void proj_v9(const float* __restrict__ x, const short* __restrict__ Wb3,
             short* __restrict__ q, short* __restrict__ k, short* __restrict__ vt)
{
    __shared__ float As[32 * 64];        // 8 KB fp32, swizzled 16B units
    __shared__ short Bs[1536 * 8];       // 24 KB bf16, frag-ordered
    const int t = threadIdx.x;
    const int l = t & 63;
    const int w = t >> 6;
    const int wm = w & 1, wn = w >> 1;   // 2 M-groups x 4 N-groups
    const int l15 = l & 15, g = l >> 4;
    const long row0 = (long)blockIdx.x * 32;

    const int arow = wm * 16 + l15;      // A-frag row (lane)
    const int aswz = arow & 7;

    f32x4 acc0 = {0,0,0,0}, acc1 = {0,0,0,0}, acc2 = {0,0,0,0};

    // staging addresses (constant per thread, advance by step)
    const int ar = t >> 4, acu = t & 15;                 // A: unit t
    const float* agp = x + (row0 + ar) * E + ((acu ^ (ar & 7)) << 2);

    for (int s = 0; s < 16; ++s) {
        __syncthreads();   // previous step's readers done
        // ---- stage A: 512 units of 16B, 1/thread, source-swizzled ----
        __builtin_amdgcn_global_load_lds(
            (const __attribute__((address_space(1))) void*)(agp + s * 64),
            (__attribute__((address_space(3))) void*)&As[t * 4], 16, 0, 0);
        // ---- stage B: 1536 units, 3/thread, contiguous ----
        {
            const short* gb = Wb3 + (size_t)s * 1536 * 8;
            #pragma unroll
            for (int i = 0; i < 3; ++i) {
                const int u = i * 512 + t;
                __builtin_amdgcn_global_load_lds(
                    (const __attribute__((address_space(1))) void*)(gb + (size_t)u * 8),
                    (__attribute__((address_space(3))) void*)&Bs[u * 8], 16, 0, 0);
            }
        }
        __syncthreads();   // staging visible (vmcnt(0) drained by compiler)
        // ---- compute: 2 kc x 3 nfrags ----
        #pragma unroll
        for (int kc = 0; kc < 2; ++kc) {
            const int cu0 = kc * 8 + g * 2;
            float4 xa = *(const float4*)&As[(arow * 16 + (cu0 ^ aswz)) * 4];
            float4 xb = *(const float4*)&As[(arow * 16 + ((cu0 + 1) ^ aswz)) * 4];
            bf16x8 af = cvt8(xa, xb);
            bf16x8 b0 = *(const bf16x8*)&Bs[((kc * 12 + wn * 3 + 0) * 64 + l) * 8];
            bf16x8 b1 = *(const bf16x8*)&Bs[((kc * 12 + wn * 3 + 1) * 64 + l) * 8];
            bf16x8 b2 = *(const bf16x8*)&Bs[((kc * 12 + wn * 3 + 2) * 64 + l) * 8];
            acc0 = __builtin_amdgcn_mfma_f32_16x16x32_bf16(af, b0, acc0, 0, 0, 0);
            acc1 = __builtin_amdgcn_mfma_f32_16x16x32_bf16(af, b1, acc1, 0, 0, 0);
            acc2 = __builtin_amdgcn_mfma_f32_16x16x32_bf16(af, b2, acc2, 0, 0, 0);
        }
    }

    // ---- epilogue: C frag (col=l15, row=g*4+r) ----
    const long trow = row0 + wm * 16 + g * 4;
    const long bb   = trow >> 11;
    const int  t0   = (int)(trow & 2047);
    #pragma unroll
    for (int ni = 0; ni < 3; ++ni) {
        const f32x4 acc = (ni == 0) ? acc0 : (ni == 1) ? acc1 : acc2;
        const int n = wn * 48 + ni * 16 + l15;
        const int m = n >> 6;
        const int h = n & 63;
        if (m == 2) {
            short4v pkt;
            #pragma unroll
            for (int r = 0; r < 4; ++r) pkt[r] = f2bf(acc[r]);
            *(short4v*)&vt[(bb * 64 + h) * TT + t0] = pkt;
        } else {
            short* base = (m == 0) ? q : k;
            // fold 1/sqrt(H) AND log2(e) into q -> softmax uses exp2
            const float sc = (m == 0) ? (0.125f * 1.44269504f) : 1.0f;
            #pragma unroll
            for (int r = 0; r < 4; ++r)
                base[(trow + r) * 64 + h] = f2bf(acc[r] * sc);
        }
    }
}

// ---- 32x32 swapped-QK^T flash attention (unchanged) ----
__global__ __launch_bounds__(512)
void attn_v8(const short* __restrict__ qg,
             const short* __restrict__ kg,
             const short* __restrict__ vtg,
             float* __restrict__ out)
{
    __shared__ float Op[8][32][66];
    __shared__ float Ml[8][32][2];

    const int t   = threadIdx.x;
    const int L   = t & 63;
    const int w   = t >> 6;
    const int bid = blockIdx.x;
    const int b   = bid & 7;
    const int pr  = bid >> 3;
    const int l31 = L & 31, hi = L >> 5;

    const int stA = pr, stB = 63 - pr;
    const int nA = stA + 1;
    int WA = (8 * nA + 32) / 65;
    WA = WA < 1 ? 1 : (WA > 7 ? 7 : WA);
    const int WB = 8 - WA;

    const bool isB  = (w >= WA);
    const int  st   = isB ? stB : stA;
    const int  q0   = st * 32;
    const int  strd = isB ? WB : WA;
    const int  c0   = isB ? (w - WA) : w;

    bf16x8 qf[4];
    {
        const short* qp = qg + ((long)b * TT + q0 + l31) * 64 + hi * 8;
        qf[0] = *(const bf16x8*)(qp);
        qf[1] = *(const bf16x8*)(qp + 16);
        qf[2] = *(const bf16x8*)(qp + 32);
        qf[3] = *(const bf16x8*)(qp + 48);
    }

    f32x16 o0 = {}, o1 = {};
    float mrun = -1e30f, lrun = 0.f;

    const short* kbase = kg  + ((long)b * TT + l31) * 64 + hi * 8;
    const short* vbase = vtg + ((long)b * 64 + l31) * TT + hi * 8;

    for (int ci = c0; ci <= st; ci += strd) {
        const int kvs = ci * 32;
        const short* kp = kbase + (long)kvs * 64;
        bf16x8 kf0 = *(const bf16x8*)(kp);
        bf16x8 kf1 = *(const bf16x8*)(kp + 16);
        bf16x8 kf2 = *(const bf16x8*)(kp + 32);
        bf16x8 kf3 = *(const bf16x8*)(kp + 48);
        const short* vp = vbase + kvs;
        bf16x8 vf00 = *(const bf16x8*)(vp);
        bf16x8 vf01 = *(const bf16x8*)(vp + 16);
        bf16x8 vf10 = *(const bf16x8*)(vp + 32 * TT);
        bf16x8 vf11 = *(const bf16x8*)(vp + 32 * TT + 16);

        f32x16 s = {};
        __builtin_amdgcn_s_setprio(1);
        s = __builtin_amdgcn_mfma_f32_32x32x16_bf16(kf0, qf[0], s, 0, 0, 0);
        s = __builtin_amdgcn_mfma_f32_32x32x16_bf16(kf1, qf[1], s, 0, 0, 0);
        s = __builtin_amdgcn_mfma_f32_32x32x16_bf16(kf2, qf[2], s, 0, 0, 0);
        s = __builtin_amdgcn_mfma_f32_32x32x16_bf16(kf3, qf[3], s, 0, 0, 0);
        __builtin_amdgcn_s_setprio(0);

        if (kvs == q0) {
            #pragma unroll
            for (int r = 0; r < 16; ++r) {
                const int crow = (r & 3) + 8 * (r >> 2) + 4 * hi;
                if (crow > l31) s[r] = -1e30f;
            }
        }
        float m01 = fmaxf(s[0], s[1]),   m23 = fmaxf(s[2], s[3]);
        float m45 = fmaxf(s[4], s[5]),   m67 = fmaxf(s[6], s[7]);
        float m89 = fmaxf(s[8], s[9]),   mab = fmaxf(s[10], s[11]);
        float mcd = fmaxf(s[12], s[13]), mef = fmaxf(s[14], s[15]);
        float mloc = fmaxf(fmaxf(fmaxf(m01, m23), fmaxf(m45, m67)),
                           fmaxf(fmaxf(m89, mab), fmaxf(mcd, mef)));
        mloc = fmaxf(mloc, __shfl_xor(mloc, 32));
        if (__any(mloc > mrun + 8.f)) {
            const float mnew = fmaxf(mrun, mloc);
            const float a = fexp2(mrun - mnew);
            mrun = mnew;
            lrun *= a;
            #pragma unroll
            for (int r = 0; r < 16; ++r) { o0[r] *= a; o1[r] *= a; }
        }
        #pragma unroll
        for (int r = 0; r < 16; ++r) s[r] = fexp2(s[r] - mrun);
        {
            float s01 = (s[0] + s[1]) + (s[2] + s[3]);
            float s23 = (s[4] + s[5]) + (s[6] + s[7]);
            float s45 = (s[8] + s[9]) + (s[10] + s[11]);
            float s67 = (s[12] + s[13]) + (s[14] + s[15]);
            float lsum = (s01 + s23) + (s45 + s67);
            lsum += __shfl_xor(lsum, 32);
            lrun += lsum;
        }
        unsigned wv[8];
        #pragma unroll
        for (int i = 0; i < 8; ++i)
            asm("v_cvt_pk_bf16_f32 %0, %1, %2" : "=v"(wv[i]) : "v"(s[2 * i]), "v"(s[2 * i + 1]));
        unsigned p00 = wv[0], p02 = wv[2];
        unsigned p01 = wv[1], p03 = wv[3];
        unsigned p10 = wv[4], p12 = wv[6];
        unsigned p11 = wv[5], p13 = wv[7];
        asm("v_permlane32_swap_b32 %0, %1" : "+v"(p00), "+v"(p02));
        asm("v_permlane32_swap_b32 %0, %1" : "+v"(p01), "+v"(p03));
        asm("v_permlane32_swap_b32 %0, %1" : "+v"(p10), "+v"(p12));
        asm("v_permlane32_swap_b32 %0, %1" : "+v"(p11), "+v"(p13));
        u32x4 pb0u = {p00, p01, p02, p03};
        u32x4 pb1u = {p10, p11, p12, p13};
        bf16x8 pb0, pb1;
        __builtin_memcpy(&pb0, &pb0u, 16);
        __builtin_memcpy(&pb1, &pb1u, 16);
        __builtin_amdgcn_s_setprio(1);
        o0 = __builtin_amdgcn_mfma_f32_32x32x16_bf16(vf00, pb0, o0, 0, 0, 0);
        o0 = __builtin_amdgcn_mfma_f32_32x32x16_bf16(vf01, pb1, o0, 0, 0, 0);
        o1 = __builtin_amdgcn_mfma_f32_32x32x16_bf16(vf10, pb0, o1, 0, 0, 0);
        o1 = __builtin_amdgcn_mfma_f32_32x32x16_bf16(vf11, pb1, o1, 0, 0, 0);
        __builtin_amdgcn_s_setprio(0);
    }

    #pragma unroll
    for (int r = 0; r < 16; ++r) {
        const int h = (r & 3) + 8 * (r >> 2) + 4 * hi;
        Op[w][l31][h]      = o0[r];
        Op[w][l31][32 + h] = o1[r];
    }
    if (hi == 0) {
        Ml[w][l31][0] = mrun;
        Ml[w][l31][1] = lrun;
    }
    __syncthreads();

    {
        const bool tb   = (w >= 4);
        const int  base = tb ? WA : 0;
        const int  cnt  = tb ? WB : WA;
        const long oq0  = (long)(tb ? stB : stA) * 32;
        #pragma unroll
        for (int rr = 0; rr < 8; ++rr) {
            const int row = (w & 3) * 8 + rr;
            float M = -1e30f;
            for (int j = 0; j < cnt; ++j)
                M = fmaxf(M, Ml[base + j][row][0]);
            float Ls = 0.f, val = 0.f;
            for (int j = 0; j < cnt; ++j) {
                const float a = fexp2(Ml[base + j][row][0] - M);
                Ls  += a * Ml[base + j][row][1];
                val += a * Op[base + j][row][L];
            }
            out[((long)b * TT + oq0 + row) * 64 + L] = val / Ls;
        }
    }
}

extern "C" void kernel_launch(void* const* d_in, const int* in_sizes, int n_in,
                              void* d_out, int out_size, void* d_ws, size_t ws_size,
                              hipStream_t stream)
{
    const float* x  = (const float*)d_in[0];
    const float* Wq = (const float*)d_in[1];
    const float* Wk = (const float*)d_in[2];
    const float* Wv = (const float*)d_in[3];
    float* out = (float*)d_out;

    const size_t n = (size_t)BB * TT * H;   // 1,048,576 per tensor
    short* q   = (short*)d_ws;
    short* k   = q + n;
    short* vt  = k + n;                     // V transposed: [B][H][T]
    short* Wb3 = vt + n;                    // 196,608 shorts

    pack_w3 <<<dim3(96),  256, 0, stream>>>(Wq, Wk, Wv, Wb3);
    proj_v9 <<<dim3(512), 512, 0, stream>>>(x, Wb3, q, k, vt);
    attn_v8 <<<dim3(256), 512, 0, stream>>>(q, k, vt, out);
}

// Round 18
// 51.495 us; speedup vs baseline: 2.9969x; 1.0089x over previous
//
#include <hip/hip_runtime.h>

#define E  1024
#define H  64
#define BB 8
#define TT 2048

typedef __attribute__((ext_vector_type(8)))  short bf16x8;
typedef __attribute__((ext_vector_type(4)))  float f32x4;
typedef __attribute__((ext_vector_type(16))) float f32x16;
typedef __attribute__((ext_vector_type(8)))  short short8;
typedef __attribute__((ext_vector_type(4)))  short short4v;
typedef __attribute__((ext_vector_type(4)))  unsigned u32x4;

__device__ __forceinline__ short f2bf(float f) {
    union { float f; unsigned u; } v; v.f = f;
    unsigned r = v.u + 0x7FFFu + ((v.u >> 16) & 1u);   // RNE
    return (short)(r >> 16);
}

// fast 2^x via the HW transcendental (no HIP __exp2f intrinsic exists)
__device__ __forceinline__ float fexp2(float x) {
    float r;
    asm("v_exp_f32 %0, %1" : "=v"(r) : "v"(x));
    return r;
}

// 8 fp32 -> bf16x8 via 4x v_cvt_pk_bf16_f32
__device__ __forceinline__ bf16x8 cvt8(float4 a0, float4 a1) {
    unsigned w0, w1, w2, w3;
    asm("v_cvt_pk_bf16_f32 %0, %1, %2" : "=v"(w0) : "v"(a0.x), "v"(a0.y));
    asm("v_cvt_pk_bf16_f32 %0, %1, %2" : "=v"(w1) : "v"(a0.z), "v"(a0.w));
    asm("v_cvt_pk_bf16_f32 %0, %1, %2" : "=v"(w2) : "v"(a1.x), "v"(a1.y));
    asm("v_cvt_pk_bf16_f32 %0, %1, %2" : "=v"(w3) : "v"(a1.z), "v"(a1.w));
    u32x4 u = {w0, w1, w2, w3};
    bf16x8 r;
    __builtin_memcpy(&r, &u, 16);
    return r;
}

// ---- pack W into per-K-step, frag-ordered CONTIGUOUS blocks (16x16x32 B) ----
__global__ __launch_bounds__(256)
void pack_w3(const float* __restrict__ Wq, const float* __restrict__ Wk,
             const float* __restrict__ Wv, short* __restrict__ Wb3)
{
    const int t  = blockIdx.x * 256 + threadIdx.x;   // 24576 total
    const int l  = t & 63;
    const int f  = (t >> 6) % 12;
    const int sc = t / 768;                          // s*2+kc, 0..31
    const int n  = f * 16 + (l & 15);
    const int m  = n >> 6, nn = n & 63;
    const float* W = (m == 0) ? Wq : (m == 1 ? Wk : Wv);
    const int k0 = sc * 32 + ((l >> 4) << 3);
    short8 o;
    #pragma unroll
    for (int j = 0; j < 8; ++j) o[j] = f2bf(W[(k0 + j) * 64 + nn]);
    *(short8*)&Wb3[(size_t)t * 8] = o;
}

// ---- proj v10: v9 + double-buffered LDS staging (minimal 2-phase, T3) ----
// Stage s+1 issued into buf^1 BEFORE compute of s from buf -> HBM latency
// hides under compute + the sibling block; ONE barrier per step (drains the
// stage AND protects the read buffer). 64 KB LDS -> 2 blocks/CU.
__global__ __launch_bounds__(512)
void proj_v10(const float* __restrict__ x, const short* __restrict__ Wb3,
              short* __restrict__ q, short* __restrict__ k, short* __restrict__ vt)
{
    __shared__ float As[2][32 * 64];     // 2 x 8 KB fp32, swizzled 16B units
    __shared__ short Bs[2][1536 * 8];    // 2 x 24 KB bf16, frag-ordered
    const int t = threadIdx.x;
    const int l = t & 63;
    const int w = t >> 6;
    const int wm = w & 1, wn = w >> 1;   // 2 M-groups x 4 N-groups
    const int l15 = l & 15, g = l >> 4;
    const long row0 = (long)blockIdx.x * 32;

    const int arow = wm * 16 + l15;      // A-frag row (lane)
    const int aswz = arow & 7;

    f32x4 acc0 = {0,0,0,0}, acc1 = {0,0,0,0}, acc2 = {0,0,0,0};

    // staging addresses (constant per thread, advance by step)
    const int ar = t >> 4, acu = t & 15;                 // A: unit t
    const float* agp = x + (row0 + ar) * E + ((acu ^ (ar & 7)) << 2);

    // ---- prologue: stage step 0 into buffer 0 ----
    __builtin_amdgcn_global_load_lds(
        (const __attribute__((address_space(1))) void*)(agp),
        (__attribute__((address_space(3))) void*)&As[0][t * 4], 16, 0, 0);
    #pragma unroll
    for (int i = 0; i < 3; ++i) {
        const int u = i * 512 + t;
        __builtin_amdgcn_global_load_lds(
            (const __attribute__((address_space(1))) void*)(Wb3 + (size_t)u * 8),
            (__attribute__((address_space(3))) void*)&Bs[0][u * 8], 16, 0, 0);
    }
    __syncthreads();

    int cur = 0;
    for (int s = 0; s < 16; ++s) {
        // ---- issue stage s+1 into the other buffer BEFORE compute ----
        if (s + 1 < 16) {
            const int nxt = cur ^ 1;
            __builtin_amdgcn_global_load_lds(
                (const __attribute__((address_space(1))) void*)(agp + (s + 1) * 64),
                (__attribute__((address_space(3))) void*)&As[nxt][t * 4], 16, 0, 0);
            const short* gb = Wb3 + (size_t)(s + 1) * 1536 * 8;
            #pragma unroll
            for (int i = 0; i < 3; ++i) {
                const int u = i * 512 + t;
                __builtin_amdgcn_global_load_lds(
                    (const __attribute__((address_space(1))) void*)(gb + (size_t)u * 8),
                    (__attribute__((address_space(3))) void*)&Bs[nxt][u * 8], 16, 0, 0);
            }
        }
        // ---- compute step s from buf cur: 2 kc x 3 nfrags ----
        #pragma unroll
        for (int kc = 0; kc < 2; ++kc) {
            const int cu0 = kc * 8 + g * 2;
            float4 xa = *(const float4*)&As[cur][(arow * 16 + (cu0 ^ aswz)) * 4];
            float4 xb = *(const float4*)&As[cur][(arow * 16 + ((cu0 + 1) ^ aswz)) * 4];
            bf16x8 af = cvt8(xa, xb);
            bf16x8 b0 = *(const bf16x8*)&Bs[cur][((kc * 12 + wn * 3 + 0) * 64 + l) * 8];
            bf16x8 b1 = *(const bf16x8*)&Bs[cur][((kc * 12 + wn * 3 + 1) * 64 + l) * 8];
            bf16x8 b2 = *(const bf16x8*)&Bs[cur][((kc * 12 + wn * 3 + 2) * 64 + l) * 8];
            acc0 = __builtin_amdgcn_mfma_f32_16x16x32_bf16(af, b0, acc0, 0, 0, 0);
            acc1 = __builtin_amdgcn_mfma_f32_16x16x32_bf16(af, b1, acc1, 0, 0, 0);
            acc2 = __builtin_amdgcn_mfma_f32_16x16x32_bf16(af, b2, acc2, 0, 0, 0);
        }
        __syncthreads();   // stage s+1 landed; all reads of buf cur done
        cur ^= 1;
    }

    // ---- epilogue: C frag (col=l15, row=g*4+r) ----
    const long trow = row0 + wm * 16 + g * 4;
    const long bb   = trow >> 11;
    const int  t0   = (int)(trow & 2047);
    #pragma unroll
    for (int ni = 0; ni < 3; ++ni) {
        const f32x4 acc = (ni == 0) ? acc0 : (ni == 1) ? acc1 : acc2;
        const int n = wn * 48 + ni * 16 + l15;
        const int m = n >> 6;
        const int h = n & 63;
        if (m == 2) {
            short4v pkt;
            #pragma unroll
            for (int r = 0; r < 4; ++r) pkt[r] = f2bf(acc[r]);
            *(short4v*)&vt[(bb * 64 + h) * TT + t0] = pkt;
        } else {
            short* base = (m == 0) ? q : k;
            // fold 1/sqrt(H) AND log2(e) into q -> softmax uses exp2
            const float sc = (m == 0) ? (0.125f * 1.44269504f) : 1.0f;
            #pragma unroll
            for (int r = 0; r < 4; ++r)
                base[(trow + r) * 64 + h] = f2bf(acc[r] * sc);
        }
    }
}

// ---- 32x32 swapped-QK^T flash attention (unchanged) ----
__global__ __launch_bounds__(512)
void attn_v8(const short* __restrict__ qg,
             const short* __restrict__ kg,
             const short* __restrict__ vtg,
             float* __restrict__ out)
{
    __shared__ float Op[8][32][66];
    __shared__ float Ml[8][32][2];

    const int t   = threadIdx.x;
    const int L   = t & 63;
    const int w   = t >> 6;
    const int bid = blockIdx.x;
    const int b   = bid & 7;
    const int pr  = bid >> 3;
    const int l31 = L & 31, hi = L >> 5;

    const int stA = pr, stB = 63 - pr;
    const int nA = stA + 1;
    int WA = (8 * nA + 32) / 65;
    WA = WA < 1 ? 1 : (WA > 7 ? 7 : WA);
    const int WB = 8 - WA;

    const bool isB  = (w >= WA);
    const int  st   = isB ? stB : stA;
    const int  q0   = st * 32;
    const int  strd = isB ? WB : WA;
    const int  c0   = isB ? (w - WA) : w;

    bf16x8 qf[4];
    {
        const short* qp = qg + ((long)b * TT + q0 + l31) * 64 + hi * 8;
        qf[0] = *(const bf16x8*)(qp);
        qf[1] = *(const bf16x8*)(qp + 16);
        qf[2] = *(const bf16x8*)(qp + 32);
        qf[3] = *(const bf16x8*)(qp + 48);
    }

    f32x16 o0 = {}, o1 = {};
    float mrun = -1e30f, lrun = 0.f;

    const short* kbase = kg  + ((long)b * TT + l31) * 64 + hi * 8;
    const short* vbase = vtg + ((long)b * 64 + l31) * TT + hi * 8;

    for (int ci = c0; ci <= st; ci += strd) {
        const int kvs = ci * 32;
        const short* kp = kbase + (long)kvs * 64;
        bf16x8 kf0 = *(const bf16x8*)(kp);
        bf16x8 kf1 = *(const bf16x8*)(kp + 16);
        bf16x8 kf2 = *(const bf16x8*)(kp + 32);
        bf16x8 kf3 = *(const bf16x8*)(kp + 48);
        const short* vp = vbase + kvs;
        bf16x8 vf00 = *(const bf16x8*)(vp);
        bf16x8 vf01 = *(const bf16x8*)(vp + 16);
        bf16x8 vf10 = *(const bf16x8*)(vp + 32 * TT);
        bf16x8 vf11 = *(const bf16x8*)(vp + 32 * TT + 16);

        f32x16 s = {};
        __builtin_amdgcn_s_setprio(1);
        s = __builtin_amdgcn_mfma_f32_32x32x16_bf16(kf0, qf[0], s, 0, 0, 0);
        s = __builtin_amdgcn_mfma_f32_32x32x16_bf16(kf1, qf[1], s, 0, 0, 0);
        s = __builtin_amdgcn_mfma_f32_32x32x16_bf16(kf2, qf[2], s, 0, 0, 0);
        s = __builtin_amdgcn_mfma_f32_32x32x16_bf16(kf3, qf[3], s, 0, 0, 0);
        __builtin_amdgcn_s_setprio(0);

        if (kvs == q0) {
            #pragma unroll
            for (int r = 0; r < 16; ++r) {
                const int crow = (r & 3) + 8 * (r >> 2) + 4 * hi;
                if (crow > l31) s[r] = -1e30f;
            }
        }
        float m01 = fmaxf(s[0], s[1]),   m23 = fmaxf(s[2], s[3]);
        float m45 = fmaxf(s[4], s[5]),   m67 = fmaxf(s[6], s[7]);
        float m89 = fmaxf(s[8], s[9]),   mab = fmaxf(s[10], s[11]);
        float mcd = fmaxf(s[12], s[13]), mef = fmaxf(s[14], s[15]);
        float mloc = fmaxf(fmaxf(fmaxf(m01, m23), fmaxf(m45, m67)),
                           fmaxf(fmaxf(m89, mab), fmaxf(mcd, mef)));
        mloc = fmaxf(mloc, __shfl_xor(mloc, 32));
        if (__any(mloc > mrun + 8.f)) {
            const float mnew = fmaxf(mrun, mloc);
            const float a = fexp2(mrun - mnew);
            mrun = mnew;
            lrun *= a;
            #pragma unroll
            for (int r = 0; r < 16; ++r) { o0[r] *= a; o1[r] *= a; }
        }
        #pragma unroll
        for (int r = 0; r < 16; ++r) s[r] = fexp2(s[r] - mrun);
        {
            float s01 = (s[0] + s[1]) + (s[2] + s[3]);
            float s23 = (s[4] + s[5]) + (s[6] + s[7]);
            float s45 = (s[8] + s[9]) + (s[10] + s[11]);
            float s67 = (s[12] + s[13]) + (s[14] + s[15]);
            float lsum = (s01 + s23) + (s45 + s67);
            lsum += __shfl_xor(lsum, 32);
            lrun += lsum;
        }
        unsigned wv[8];
        #pragma unroll
        for (int i = 0; i < 8; ++i)
            asm("v_cvt_pk_bf16_f32 %0, %1, %2" : "=v"(wv[i]) : "v"(s[2 * i]), "v"(s[2 * i + 1]));
        unsigned p00 = wv[0], p02 = wv[2];
        unsigned p01 = wv[1], p03 = wv[3];
        unsigned p10 = wv[4], p12 = wv[6];
        unsigned p11 = wv[5], p13 = wv[7];
        asm("v_permlane32_swap_b32 %0, %1" : "+v"(p00), "+v"(p02));
        asm("v_permlane32_swap_b32 %0, %1" : "+v"(p01), "+v"(p03));
        asm("v_permlane32_swap_b32 %0, %1" : "+v"(p10), "+v"(p12));
        asm("v_permlane32_swap_b32 %0, %1" : "+v"(p11), "+v"(p13));
        u32x4 pb0u = {p00, p01, p02, p03};
        u32x4 pb1u = {p10, p11, p12, p13};
        bf16x8 pb0, pb1;
        __builtin_memcpy(&pb0, &pb0u, 16);
        __builtin_memcpy(&pb1, &pb1u, 16);
        __builtin_amdgcn_s_setprio(1);
        o0 = __builtin_amdgcn_mfma_f32_32x32x16_bf16(vf00, pb0, o0, 0, 0, 0);
        o0 = __builtin_amdgcn_mfma_f32_32x32x16_bf16(vf01, pb1, o0, 0, 0, 0);
        o1 = __builtin_amdgcn_mfma_f32_32x32x16_bf16(vf10, pb0, o1, 0, 0, 0);
        o1 = __builtin_amdgcn_mfma_f32_32x32x16_bf16(vf11, pb1, o1, 0, 0, 0);
        __builtin_amdgcn_s_setprio(0);
    }

    #pragma unroll
    for (int r = 0; r < 16; ++r) {
        const int h = (r & 3) + 8 * (r >> 2) + 4 * hi;
        Op[w][l31][h]      = o0[r];
        Op[w][l31][32 + h] = o1[r];
    }
    if (hi == 0) {
        Ml[w][l31][0] = mrun;
        Ml[w][l31][1] = lrun;
    }
    __syncthreads();

    {
        const bool tb   = (w >= 4);
        const int  base = tb ? WA : 0;
        const int  cnt  = tb ? WB : WA;
        const long oq0  = (long)(tb ? stB : stA) * 32;
        #pragma unroll
        for (int rr = 0; rr < 8; ++rr) {
            const int row = (w & 3) * 8 + rr;
            float M = -1e30f;
            for (int j = 0; j < cnt; ++j)
                M = fmaxf(M, Ml[base + j][row][0]);
            float Ls = 0.f, val = 0.f;
            for (int j = 0; j < cnt; ++j) {
                const float a = fexp2(Ml[base + j][row][0] - M);
                Ls  += a * Ml[base + j][row][1];
                val += a * Op[base + j][row][L];
            }
            out[((long)b * TT + oq0 + row) * 64 + L] = val / Ls;
        }
    }
}

extern "C" void kernel_launch(void* const* d_in, const int* in_sizes, int n_in,
                              void* d_out, int out_size, void* d_ws, size_t ws_size,
                              hipStream_t stream)
{
    const float* x  = (const float*)d_in[0];
    const float* Wq = (const float*)d_in[1];
    const float* Wk = (const float*)d_in[2];
    const float* Wv = (const float*)d_in[3];
    float* out = (float*)d_out;

    const size_t n = (size_t)BB * TT * H;   // 1,048,576 per tensor
    short* q   = (short*)d_ws;
    short* k   = q + n;
    short* vt  = k + n;                     // V transposed: [B][H][T]
    short* Wb3 = vt + n;                    // 196,608 shorts

    pack_w3  <<<dim3(96),  256, 0, stream>>>(Wq, Wk, Wv, Wb3);
    proj_v10 <<<dim3(512), 512, 0, stream>>>(x, Wb3, q, k, vt);
    attn_v8  <<<dim3(256), 512, 0, stream>>>(q, k, vt, out);
}